// Round 7
// baseline (255.728 us; speedup 1.0000x reference)
//
#include <hip/hip_runtime.h>
#include <math.h>

#define H 8
#define L 4096
#define D 64
#define NBLK 64
#define TOPK 16
#define EPS 1e-5f
#define LP 68

typedef unsigned short u16;
typedef unsigned int u32;
typedef __attribute__((ext_vector_type(8))) short bf16x8;
typedef __attribute__((ext_vector_type(16))) float f32x16;
typedef __attribute__((ext_vector_type(4))) u32 u32x4;

static __device__ __forceinline__ u16 f2bf(float x) {
  u32 u = __float_as_uint(x);
  u32 r = (u + 0x7fffu + ((u >> 16) & 1u)) >> 16;
  return (u16)r;
}
static __device__ __forceinline__ float bf2f(u16 h) {
  return __uint_as_float(((u32)h) << 16);
}
__device__ __forceinline__ float dot4f(float4 a, float4 b) {
  return a.x * b.x + a.y * b.y + a.z * b.z + a.w * b.w;
}

// ---------------------------------------------------------------------------
// KVPREP: fused kpack + vpack + pool_k + kvacc-partial (unchanged).
// ---------------------------------------------------------------------------
__global__ __launch_bounds__(256) void kvprep_kernel(
    const float* __restrict__ k, const float* __restrict__ v,
    u16* __restrict__ kpkb, u16* __restrict__ vpkb,
    float* __restrict__ pkp, float* __restrict__ part_kv,
    float* __restrict__ part_ks) {
  const int kb = blockIdx.x, h = blockIdx.y;
  __shared__ float kst[64 * LP];
  __shared__ float vst[64 * LP];
  __shared__ float red[4][64];
  const int t = threadIdx.x;

  {
    const float4* ksrc = (const float4*)(k + ((size_t)h * L + (size_t)kb * 64) * D);
    const float4* vsrc = (const float4*)(v + ((size_t)h * L + (size_t)kb * 64) * D);
#pragma unroll
    for (int i = 0; i < 4; ++i) {
      int flat = i * 256 + t;
      int row = flat >> 4, c4 = flat & 15;
      *(float4*)&kst[row * LP + c4 * 4] = ksrc[flat];
      *(float4*)&vst[row * LP + c4 * 4] = vsrc[flat];
    }
  }
  __syncthreads();

  {
    u16* rowbase = kpkb + ((size_t)h * L + (size_t)kb * 64) * 128;
#pragma unroll
    for (int pass = 0; pass < 2; ++pass) {
      const int key = pass * 32 + (t >> 3);
      const int sub = t & 7;
      float f[8];
#pragma unroll
      for (int e = 0; e < 8; ++e) f[e] = kst[key * LP + sub * 8 + e];
      u16 hi[8], lo[8];
#pragma unroll
      for (int e = 0; e < 8; ++e) {
        hi[e] = f2bf(f[e]);
        lo[e] = f2bf(f[e] - bf2f(hi[e]));
      }
      const int c = sub >> 1, g2 = sub & 1;
      u16* row = rowbase + (size_t)key * 128;
      const int sh = ((c * 4 + g2 * 2 + 0) ^ (key & 15)) * 8;
      const int sl = ((c * 4 + g2 * 2 + 1) ^ (key & 15)) * 8;
      uint4 vh = {(u32)hi[0] | ((u32)hi[1] << 16), (u32)hi[2] | ((u32)hi[3] << 16),
                  (u32)hi[4] | ((u32)hi[5] << 16), (u32)hi[6] | ((u32)hi[7] << 16)};
      uint4 vl = {(u32)lo[0] | ((u32)lo[1] << 16), (u32)lo[2] | ((u32)lo[3] << 16),
                  (u32)lo[4] | ((u32)lo[5] << 16), (u32)lo[6] | ((u32)lo[7] << 16)};
      *(uint4*)(row + sh) = vh;
      *(uint4*)(row + sl) = vl;
    }
  }

  {
    const int d = t & 63, rr = t >> 6;
    float s = 0.f;
#pragma unroll
    for (int i = 0; i < 16; ++i) s += kst[(rr * 16 + i) * LP + d];
    red[rr][d] = s;
  }
  __syncthreads();
  {
    const int d = t & 63, rr = t >> 6;
    if (rr == 0) {
      float tot = red[0][d] + red[1][d] + red[2][d] + red[3][d];
      pkp[((size_t)h * NBLK + kb) * D + d] = tot * (1.f / 64.f);
    }
  }

  {
    u16* base = vpkb + (((size_t)h * 64 + kb) * 64) * 128;
#pragma unroll
    for (int iter = 0; iter < 4; ++iter) {
      const int dim = iter * 16 + (t >> 4);
      const int s = t & 15;
      const int cgh = s ^ (dim & 15);
      const int c = cgh >> 2, g = (cgh >> 1) & 1, hl = cgh & 1;
      u16 o[8];
#pragma unroll
      for (int e = 0; e < 8; ++e) {
        const int key = 4 * g + (e & 3) + 8 * ((e >> 2) + 2 * (c & 1)) + 32 * (c >> 1);
        float val = vst[key * LP + dim];
        u16 hi = f2bf(val);
        o[e] = hl ? f2bf(val - bf2f(hi)) : hi;
      }
      uint4 pk4 = {(u32)o[0] | ((u32)o[1] << 16), (u32)o[2] | ((u32)o[3] << 16),
                   (u32)o[4] | ((u32)o[5] << 16), (u32)o[6] | ((u32)o[7] << 16)};
      *(uint4*)(base + (size_t)dim * 128 + s * 8) = pk4;
    }
  }

  if (t < 128) {
    const int row = t >> 1, half = t & 1;
    float4 kr[8];
#pragma unroll
    for (int i = 0; i < 8; ++i) kr[i] = *(float4*)&kst[row * LP + half * 32 + i * 4];
    float mxk = -INFINITY;
#pragma unroll
    for (int i = 0; i < 8; ++i)
      mxk = fmaxf(mxk, fmaxf(fmaxf(kr[i].x, kr[i].y), fmaxf(kr[i].z, kr[i].w)));
    mxk = fmaxf(mxk, __shfl_xor(mxk, 1));
    float smk = 0.f;
#pragma unroll
    for (int i = 0; i < 8; ++i) {
      kr[i].x = __expf(kr[i].x - mxk); kr[i].y = __expf(kr[i].y - mxk);
      kr[i].z = __expf(kr[i].z - mxk); kr[i].w = __expf(kr[i].w - mxk);
      smk += kr[i].x + kr[i].y + kr[i].z + kr[i].w;
    }
    smk += __shfl_xor(smk, 1);
    const float inv = 1.f / smk;
#pragma unroll
    for (int i = 0; i < 8; ++i) {
      float4 o = kr[i];
      o.x *= inv; o.y *= inv; o.z *= inv; o.w *= inv;
      *(float4*)&kst[row * LP + half * 32 + i * 4] = o;
    }
  }
  __syncthreads();

  {
    const int d = t & 63, eg = t >> 6;
    float4 acc0 = make_float4(0.f, 0.f, 0.f, 0.f);
    float4 acc1 = acc0, acc2 = acc0, acc3 = acc0;
    float ksacc = 0.f;
#pragma unroll 4
    for (int lr = 0; lr < 64; ++lr) {
      const float wv = kst[lr * LP + d];
      if (eg == 0) ksacc += wv;
      const float4* vr = (const float4*)&vst[lr * LP + eg * 16];
      float4 v0 = vr[0], v1 = vr[1], v2 = vr[2], v3 = vr[3];
      acc0.x += wv * v0.x; acc0.y += wv * v0.y; acc0.z += wv * v0.z; acc0.w += wv * v0.w;
      acc1.x += wv * v1.x; acc1.y += wv * v1.y; acc1.z += wv * v1.z; acc1.w += wv * v1.w;
      acc2.x += wv * v2.x; acc2.y += wv * v2.y; acc2.z += wv * v2.z; acc2.w += wv * v2.w;
      acc3.x += wv * v3.x; acc3.y += wv * v3.y; acc3.z += wv * v3.z; acc3.w += wv * v3.w;
    }
    float* kvb = part_kv + ((size_t)(h * 64 + kb)) * 4096 + (size_t)d * 64 + eg * 16;
    *(float4*)(kvb + 0) = acc0;
    *(float4*)(kvb + 4) = acc1;
    *(float4*)(kvb + 8) = acc2;
    *(float4*)(kvb + 12) = acc3;
    if (eg == 0) part_ks[(size_t)(h * 64 + kb) * 64 + d] = ksacc;
  }
}

// ---------------------------------------------------------------------------
// pool (q only)
// ---------------------------------------------------------------------------
__global__ __launch_bounds__(256) void pool_kernel(
    const float* __restrict__ src, float* __restrict__ dst) {
  const int blk = blockIdx.x, h = blockIdx.y;
  const int d = threadIdx.x & 63, rr = threadIdx.x >> 6;
  const float* base = src + ((size_t)h * L + (size_t)blk * 64) * D;
  float s = 0.f;
#pragma unroll
  for (int i = 0; i < 16; ++i) s += base[(rr * 16 + i) * D + d];
  __shared__ float red[4][64];
  red[rr][d] = s;
  __syncthreads();
  if (rr == 0) {
    float tot = red[0][d] + red[1][d] + red[2][d] + red[3][d];
    dst[((size_t)h * NBLK + blk) * D + d] = tot * (1.f / 64.f);
  }
}

// ---------------------------------------------------------------------------
// topk (unchanged)
// ---------------------------------------------------------------------------
__global__ __launch_bounds__(64) void topk_kernel(
    const float* __restrict__ pq, const float* __restrict__ pk,
    int* __restrict__ lut) {
  const int qb = blockIdx.x, h = blockIdx.y;
  const int j = threadIdx.x;
  const float4* pqv = (const float4*)(pq + ((size_t)h * NBLK + qb) * D);
  const float4* pkv = (const float4*)(pk + ((size_t)h * NBLK + j) * D);
  float s = 0.f;
#pragma unroll
  for (int d4 = 0; d4 < 16; ++d4) s += dot4f(pqv[d4], pkv[d4]);
  int* lrow = lut + ((size_t)h * NBLK + qb) * TOPK;
  for (int t = 0; t < TOPK; ++t) {
    float m = s;
    int mi = j;
#pragma unroll
    for (int off = 32; off; off >>= 1) {
      float om = __shfl_xor(m, off);
      int omi = __shfl_xor(mi, off);
      if (om > m || (om == m && omi < mi)) { m = om; mi = omi; }
    }
    if (j == 0) lrow[t] = mi;
    if (j == mi) s = -INFINITY;
  }
}

// ---------------------------------------------------------------------------
// SATTN v4: TOPK split across 2 blocks (8 kb each) + single 32KB LDS buffer
// with reg-staged prefetch (T14) -> 4 blocks/CU, 16 waves/CU.
// Partial O/l are PLAIN SUMS (no-max softmax) -> merged in linattn.
// grid 1024: h = bx&7, qb = (bx>>3)&63, hs = bx>>9.
// ---------------------------------------------------------------------------
__global__ __launch_bounds__(256, 4) void sattn_kernel(
    const float* __restrict__ q, const u16* __restrict__ kpk,
    const u16* __restrict__ vpk, const int* __restrict__ lut,
    float* __restrict__ part_o, float* __restrict__ part_l) {
  __shared__ alignas(16) char smem[32768];  // K 16KB | V 16KB (single buffer)
  const int bx = blockIdx.x;
  const int h = bx & 7;            // XCD swizzle: head -> one XCD's L2
  const int qb = (bx >> 3) & 63;
  const int hs = bx >> 9;          // which 8 of the top-16 blocks
  const int t = threadIdx.x;
  const int lane = t & 63;
  const int ln = lane & 31;
  const int g = lane >> 5;
  const int w = t >> 6;
  const int p = w & 1;
  const int kh = w >> 1;

  // --- Q hi/lo fragments straight from global (L2-hot) ---
  bf16x8 qh[4], ql[4];
  {
    const float* qrowp = q + ((size_t)h * L + (size_t)qb * 64 + p * 32 + ln) * D;
#pragma unroll
    for (int c = 0; c < 4; ++c) {
      float4 a = *(const float4*)(qrowp + c * 16 + g * 8);
      float4 b = *(const float4*)(qrowp + c * 16 + g * 8 + 4);
      float f[8] = {a.x, a.y, a.z, a.w, b.x, b.y, b.z, b.w};
#pragma unroll
      for (int e = 0; e < 8; ++e) {
        float x = f[e] * 0.125f;
        u16 hi = f2bf(x);
        qh[c][e] = (short)hi;
        ql[c][e] = (short)f2bf(x - bf2f(hi));
      }
    }
  }

  uint4* lk = (uint4*)smem;        // 1024 uint4 (K tile)
  uint4* lv = lk + 1024;           // 1024 uint4 (V tile)
  const u16* KB = (const u16*)smem;
  const u16* VB = (const u16*)smem + 8192;

  f32x16 o0, o1;
#pragma unroll
  for (int r = 0; r < 16; ++r) { o0[r] = 0.f; o1[r] = 0.f; }
  float lrun = 0.f;
  const int* lrow = lut + ((size_t)h * NBLK + qb) * TOPK + hs * 8;
  const int xr = ln & 15;
  const int krow = kh * 32 + ln;

  uint4 pf[8];
#define LOADR(kbi)                                                               \
  {                                                                              \
    const int kb_ = (kbi);                                                       \
    const uint4* gk = (const uint4*)(kpk + ((size_t)h * L + (size_t)kb_ * 64) * 128); \
    const uint4* gv = (const uint4*)(vpk + (((size_t)h * 64 + kb_) * 64) * 128);      \
    _Pragma("unroll") for (int i_ = 0; i_ < 4; ++i_) pf[i_] = gk[i_ * 256 + t];  \
    _Pragma("unroll") for (int i_ = 0; i_ < 4; ++i_) pf[4 + i_] = gv[i_ * 256 + t]; \
  }
#define WRITES                                                                   \
  {                                                                              \
    _Pragma("unroll") for (int i_ = 0; i_ < 4; ++i_) lk[i_ * 256 + t] = pf[i_];  \
    _Pragma("unroll") for (int i_ = 0; i_ < 4; ++i_) lv[i_ * 256 + t] = pf[4 + i_]; \
  }

  LOADR(lrow[0]);
  WRITES;            // compiler waits vmcnt before use
  LOADR(lrow[1]);    // prefetch tile 1 into regs
  __syncthreads();

  for (int ib = 0; ib < 8; ++ib) {
    // ---- S^T = K . Q^T over this wave's 32-key half ----
    f32x16 s0;
#pragma unroll
    for (int r = 0; r < 16; ++r) s0[r] = 0.f;
    __builtin_amdgcn_s_setprio(1);
#pragma unroll
    for (int c = 0; c < 4; ++c) {
      const int sH = c * 4 + g * 2;
      bf16x8 k_h = *(const bf16x8*)(KB + (size_t)krow * 128 + ((sH ^ xr) * 8));
      bf16x8 k_l = *(const bf16x8*)(KB + (size_t)krow * 128 + (((sH + 1) ^ xr) * 8));
      s0 = __builtin_amdgcn_mfma_f32_32x32x16_bf16(k_h, qh[c], s0, 0, 0, 0);
      s0 = __builtin_amdgcn_mfma_f32_32x32x16_bf16(k_l, qh[c], s0, 0, 0, 0);
      s0 = __builtin_amdgcn_mfma_f32_32x32x16_bf16(k_h, ql[c], s0, 0, 0, 0);
    }
    __builtin_amdgcn_s_setprio(0);

    // ---- P = exp(S) (no max; scores bounded), pack hi/lo via cvt_pk ----
    u32 hpk[8], lpk[8];
    float psum = 0.f;
#pragma unroll
    for (int j = 0; j < 8; ++j) {
      float a = __expf(s0[2 * j]);
      float b = __expf(s0[2 * j + 1]);
      psum += a + b;
      u32 hp;
      asm("v_cvt_pk_bf16_f32 %0, %1, %2" : "=v"(hp) : "v"(a), "v"(b));
      hpk[j] = hp;
      float ah = __uint_as_float(hp << 16);
      float bh = __uint_as_float(hp & 0xffff0000u);
      u32 lp;
      asm("v_cvt_pk_bf16_f32 %0, %1, %2" : "=v"(lp) : "v"(a - ah), "v"(b - bh));
      lpk[j] = lp;
    }
    psum += __shfl_xor(psum, 32);
    lrun += psum;

    // ---- PV over this wave's key channels ----
    __builtin_amdgcn_s_setprio(1);
#pragma unroll
    for (int cc = 0; cc < 2; ++cc) {
      union { u32x4 u; bf16x8 b; } ph, pl;
      ph.u = (u32x4){hpk[4 * cc + 0], hpk[4 * cc + 1], hpk[4 * cc + 2], hpk[4 * cc + 3]};
      pl.u = (u32x4){lpk[4 * cc + 0], lpk[4 * cc + 1], lpk[4 * cc + 2], lpk[4 * cc + 3]};
      const bf16x8 pah = ph.b, pal = pl.b;
      const int sH = (2 * kh + cc) * 4 + g * 2;
      bf16x8 v0h = *(const bf16x8*)(VB + (size_t)ln * 128 + ((sH ^ xr) * 8));
      bf16x8 v0l = *(const bf16x8*)(VB + (size_t)ln * 128 + (((sH + 1) ^ xr) * 8));
      bf16x8 v1h = *(const bf16x8*)(VB + (size_t)(32 + ln) * 128 + ((sH ^ xr) * 8));
      bf16x8 v1l = *(const bf16x8*)(VB + (size_t)(32 + ln) * 128 + (((sH + 1) ^ xr) * 8));
      o0 = __builtin_amdgcn_mfma_f32_32x32x16_bf16(pah, v0h, o0, 0, 0, 0);
      o0 = __builtin_amdgcn_mfma_f32_32x32x16_bf16(pal, v0h, o0, 0, 0, 0);
      o0 = __builtin_amdgcn_mfma_f32_32x32x16_bf16(pah, v0l, o0, 0, 0, 0);
      o1 = __builtin_amdgcn_mfma_f32_32x32x16_bf16(pah, v1h, o1, 0, 0, 0);
      o1 = __builtin_amdgcn_mfma_f32_32x32x16_bf16(pal, v1h, o1, 0, 0, 0);
      o1 = __builtin_amdgcn_mfma_f32_32x32x16_bf16(pah, v1l, o1, 0, 0, 0);
    }
    __builtin_amdgcn_s_setprio(0);

    __syncthreads();                     // all reads of current tile done
    if (ib + 1 < 8) { WRITES; }          // write tile ib+1 (waits its vmcnt)
    if (ib + 2 < 8) LOADR(lrow[ib + 2]); // prefetch tile ib+2 into regs
    __syncthreads();                     // writes visible
  }
#undef LOADR
#undef WRITES

  // ---- merge kh halves (plain sums), write PARTIAL O and l ----
  float* oxbase = (float*)smem;           // [2 panels][32][64]
  float* lxbase = (float*)smem + 4096;    // [2 panels][2 kh][32]
  if (g == 0) lxbase[(p * 2 + kh) * 32 + ln] = lrun;
  if (kh == 1) {
#pragma unroll
    for (int r = 0; r < 16; ++r) {
      const int R = (r & 3) + 8 * (r >> 2) + 4 * g;
      oxbase[p * 2048 + R * 64 + ln] = o0[r];
      oxbase[p * 2048 + R * 64 + 32 + ln] = o1[r];
    }
  }
  __syncthreads();
  if (kh == 0) {
    const size_t rbase = (size_t)hs * (H * L) + (size_t)h * L + (size_t)qb * 64 + p * 32;
#pragma unroll
    for (int r = 0; r < 16; ++r) {
      const int R = (r & 3) + 8 * (r >> 2) + 4 * g;
      const float lt = lxbase[(p * 2 + 0) * 32 + R] + lxbase[(p * 2 + 1) * 32 + R];
      if (ln == 0) part_l[rbase + R] = lt;
      const size_t row = rbase + R;
      part_o[row * 64 + ln] = o0[r] + oxbase[p * 2048 + R * 64 + ln];
      part_o[row * 64 + 32 + ln] = o1[r] + oxbase[p * 2048 + R * 64 + 32 + ln];
    }
  }
}

// ---------------------------------------------------------------------------
// KVRED: stage-1 reduce of 64 partials/head -> 16/head (unchanged)
// ---------------------------------------------------------------------------
__global__ __launch_bounds__(256) void kvred_kernel(
    const float* __restrict__ part_kv, const float* __restrict__ part_ks,
    float* __restrict__ p2kv, float* __restrict__ p2ks) {
  const int j = blockIdx.x, h = blockIdx.y;
  const int t = threadIdx.x;
  float4 s0 = make_float4(0.f, 0.f, 0.f, 0.f);
  float4 s1 = s0, s2 = s0, s3 = s0;
#pragma unroll
  for (int p = 0; p < 4; ++p) {
    const float4* src = (const float4*)(part_kv + ((size_t)(h * 64 + j * 4 + p)) * 4096);
    float4 a = src[0 * 256 + t], b = src[1 * 256 + t];
    float4 c = src[2 * 256 + t], d = src[3 * 256 + t];
    s0.x += a.x; s0.y += a.y; s0.z += a.z; s0.w += a.w;
    s1.x += b.x; s1.y += b.y; s1.z += b.z; s1.w += b.w;
    s2.x += c.x; s2.y += c.y; s2.z += c.z; s2.w += c.w;
    s3.x += d.x; s3.y += d.y; s3.z += d.z; s3.w += d.w;
  }
  float4* dst = (float4*)(p2kv + ((size_t)(h * 16 + j)) * 4096);
  dst[0 * 256 + t] = s0;
  dst[1 * 256 + t] = s1;
  dst[2 * 256 + t] = s2;
  dst[3 * 256 + t] = s3;
  if (t < 64) {
    float ks = 0.f;
#pragma unroll
    for (int p = 0; p < 4; ++p) ks += part_ks[(size_t)(h * 64 + j * 4 + p) * 64 + t];
    p2ks[(size_t)(h * 16 + j) * 64 + t] = ks;
  }
}

// ---------------------------------------------------------------------------
// KVPROJ: reduce 16 partials + fold projection (unchanged)
// ---------------------------------------------------------------------------
__global__ __launch_bounds__(256) void kvproj_kernel(
    const float* __restrict__ p2kv, const float* __restrict__ p2ks,
    const float* __restrict__ pw, float* __restrict__ kvp,
    float* __restrict__ ksum) {
  const int h = blockIdx.x;
  __shared__ float kvs[64 * 64];
  __shared__ float pws[64 * 64];
  const int t = threadIdx.x;
  float4 s0 = make_float4(0.f, 0.f, 0.f, 0.f);
  float4 s1 = s0, s2 = s0, s3 = s0;
  for (int p = 0; p < 16; ++p) {
    const float4* src = (const float4*)(p2kv + ((size_t)(h * 16 + p)) * 4096);
    float4 a = src[0 * 256 + t], b = src[1 * 256 + t];
    float4 cc = src[2 * 256 + t], dd = src[3 * 256 + t];
    s0.x += a.x; s0.y += a.y; s0.z += a.z; s0.w += a.w;
    s1.x += b.x; s1.y += b.y; s1.z += b.z; s1.w += b.w;
    s2.x += cc.x; s2.y += cc.y; s2.z += cc.z; s2.w += cc.w;
    s3.x += dd.x; s3.y += dd.y; s3.z += dd.z; s3.w += dd.w;
  }
  ((float4*)kvs)[0 * 256 + t] = s0;
  ((float4*)kvs)[1 * 256 + t] = s1;
  ((float4*)kvs)[2 * 256 + t] = s2;
  ((float4*)kvs)[3 * 256 + t] = s3;
#pragma unroll
  for (int i = 0; i < 4; ++i) {
    int f4 = i * 256 + t;
    ((float4*)pws)[f4] = ((const float4*)pw)[f4];
  }
  if (t < 64) {
    float ks = 0.f;
    for (int p = 0; p < 16; ++p) ks += p2ks[(size_t)(h * 16 + p) * 64 + t];
    ksum[(size_t)h * 64 + t] = ks;
  }
  __syncthreads();
  const int d = t & 63, fg = t >> 6;
  float* dst = kvp + (size_t)h * 4096 + (size_t)d * 64;
  const float4* a = (const float4*)&kvs[d * 64];
  for (int f = fg * 16; f < fg * 16 + 16; ++f) {
    const float4* b = (const float4*)&pws[f * 64];
    float s = 0.f;
#pragma unroll
    for (int e4 = 0; e4 < 16; ++e4) s += dot4f(a[e4], b[e4]);
    dst[f] = s;
  }
}

// ---------------------------------------------------------------------------
// LINATTN: compose out = (po0+po1)/(l0+l1) + o_l + b (pure write, no RMW)
// ---------------------------------------------------------------------------
__global__ __launch_bounds__(256) void linattn_kernel(
    const float* __restrict__ q, const float* __restrict__ kvp,
    const float* __restrict__ ksum, const float* __restrict__ pb,
    const float* __restrict__ part_o, const float* __restrict__ part_l,
    float* __restrict__ out) {
  __shared__ float kvs[64 * 64];
  __shared__ float kss[64], pbs[64];
  const int t = threadIdx.x;
  const size_t grow = (size_t)blockIdx.x * 256 + t;
  const int h = (int)(grow >> 12);
#pragma unroll
  for (int i = 0; i < 4; ++i) {
    int f4 = i * 256 + t;
    ((float4*)kvs)[f4] = ((const float4*)(kvp + (size_t)h * 4096))[f4];
  }
  if (t < 64) {
    kss[t] = ksum[(size_t)h * 64 + t];
    pbs[t] = pb[t];
  }
  __syncthreads();
  const float* qrow = q + grow * 64;
  float mx = -INFINITY;
  const float4* q4p = (const float4*)qrow;
#pragma unroll
  for (int i = 0; i < 16; ++i) {
    float4 x = q4p[i];
    mx = fmaxf(mx, fmaxf(fmaxf(x.x, x.y), fmaxf(x.z, x.w)));
  }
  float4 tt[16];
#pragma unroll
  for (int i = 0; i < 16; ++i) tt[i] = make_float4(0.f, 0.f, 0.f, 0.f);
  float sm = 0.f, dn = 0.f;
#pragma unroll 4
  for (int dd = 0; dd < 64; ++dd) {
    const float wv = __expf(qrow[dd] - mx);
    sm += wv;
    dn += wv * kss[dd];
    const float4* kvr = (const float4*)&kvs[dd * 64];
#pragma unroll
    for (int e4 = 0; e4 < 16; ++e4) {
      float4 kk = kvr[e4];
      tt[e4].x += wv * kk.x; tt[e4].y += wv * kk.y;
      tt[e4].z += wv * kk.z; tt[e4].w += wv * kk.w;
    }
  }
  const float inv = 1.f / (dn + EPS * sm);
  const float sinv = 1.f / (part_l[grow] + part_l[(size_t)H * L + grow]);
  const float4* po0 = (const float4*)(part_o + grow * 64);
  const float4* po1 = (const float4*)(part_o + ((size_t)H * L + grow) * 64);
  float* orow = out + grow * 64;
#pragma unroll
  for (int e4 = 0; e4 < 16; ++e4) {
    float4 a = po0[e4], b = po1[e4];
    float4 o;
    o.x = (a.x + b.x) * sinv + tt[e4].x * inv + pbs[e4 * 4 + 0];
    o.y = (a.y + b.y) * sinv + tt[e4].y * inv + pbs[e4 * 4 + 1];
    o.z = (a.z + b.z) * sinv + tt[e4].z * inv + pbs[e4 * 4 + 2];
    o.w = (a.w + b.w) * sinv + tt[e4].w * inv + pbs[e4 * 4 + 3];
    ((float4*)orow)[e4] = o;
  }
}

// ---------------------------------------------------------------------------
extern "C" void kernel_launch(void* const* d_in, const int* in_sizes, int n_in,
                              void* d_out, int out_size, void* d_ws, size_t ws_size,
                              hipStream_t stream) {
  const float* q = (const float*)d_in[0];
  const float* k = (const float*)d_in[1];
  const float* v = (const float*)d_in[2];
  const float* pw = (const float*)d_in[3];
  const float* pb = (const float*)d_in[4];
  float* out = (float*)d_out;

  u16* kpkb = (u16*)d_ws;
  u16* vpkb = (u16*)d_ws + 4194304;
  float* fws = (float*)((char*)d_ws + 16777216);
  float* pq = fws;                       // 32768
  float* pk = fws + 32768;               // 32768
  float* part_kv = fws + 65536;          // 2097152
  float* part_ks = fws + 2162688;        // 32768
  float* p2kv = fws + 2195456;           // 524288
  float* p2ks = fws + 2719744;           // 8192
  float* kvp = fws + 2727936;            // 32768
  float* ksum = fws + 2760704;           // 512
  int* lut = (int*)(fws + 2761216);      // 8192 ints
  float* part_l = fws + 2769408;         // 65536
  float* part_o = fws + 2834944;         // 4194304 (16 MB)

  kvprep_kernel<<<dim3(64, 8), 256, 0, stream>>>(k, v, kpkb, vpkb, pk, part_kv, part_ks);
  pool_kernel<<<dim3(64, 8), 256, 0, stream>>>(q, pq);
  topk_kernel<<<dim3(64, 8), 64, 0, stream>>>(pq, pk, lut);
  sattn_kernel<<<1024, 256, 0, stream>>>(q, kpkb, vpkb, lut, part_o, part_l);
  kvred_kernel<<<dim3(16, 8), 256, 0, stream>>>(part_kv, part_ks, p2kv, p2ks);
  kvproj_kernel<<<8, 256, 0, stream>>>(p2kv, p2ks, pw, kvp, ksum);
  linattn_kernel<<<128, 256, 0, stream>>>(q, kvp, ksum, pb, part_o, part_l, out);
}

// Round 9
// 243.342 us; speedup vs baseline: 1.0509x; 1.0509x over previous
//
#include <hip/hip_runtime.h>
#include <math.h>

#define H 8
#define L 4096
#define D 64
#define NBLK 64
#define TOPK 16
#define EPS 1e-5f
#define LP 68

typedef unsigned short u16;
typedef unsigned int u32;
typedef __attribute__((ext_vector_type(8))) short bf16x8;
typedef __attribute__((ext_vector_type(16))) float f32x16;
typedef __attribute__((ext_vector_type(4))) u32 u32x4;

static __device__ __forceinline__ u16 f2bf(float x) {
  u32 u = __float_as_uint(x);
  u32 r = (u + 0x7fffu + ((u >> 16) & 1u)) >> 16;
  return (u16)r;
}
static __device__ __forceinline__ float bf2f(u16 h) {
  return __uint_as_float(((u32)h) << 16);
}
__device__ __forceinline__ float dot4f(float4 a, float4 b) {
  return a.x * b.x + a.y * b.y + a.z * b.z + a.w * b.w;
}

// ---------------------------------------------------------------------------
// KVPREP: fused kpack + vpack + pool_k + kvacc-partial (unchanged).
// ---------------------------------------------------------------------------
__global__ __launch_bounds__(256) void kvprep_kernel(
    const float* __restrict__ k, const float* __restrict__ v,
    u16* __restrict__ kpkb, u16* __restrict__ vpkb,
    float* __restrict__ pkp, float* __restrict__ part_kv,
    float* __restrict__ part_ks) {
  const int kb = blockIdx.x, h = blockIdx.y;
  __shared__ float kst[64 * LP];
  __shared__ float vst[64 * LP];
  __shared__ float red[4][64];
  const int t = threadIdx.x;

  {
    const float4* ksrc = (const float4*)(k + ((size_t)h * L + (size_t)kb * 64) * D);
    const float4* vsrc = (const float4*)(v + ((size_t)h * L + (size_t)kb * 64) * D);
#pragma unroll
    for (int i = 0; i < 4; ++i) {
      int flat = i * 256 + t;
      int row = flat >> 4, c4 = flat & 15;
      *(float4*)&kst[row * LP + c4 * 4] = ksrc[flat];
      *(float4*)&vst[row * LP + c4 * 4] = vsrc[flat];
    }
  }
  __syncthreads();

  {
    u16* rowbase = kpkb + ((size_t)h * L + (size_t)kb * 64) * 128;
#pragma unroll
    for (int pass = 0; pass < 2; ++pass) {
      const int key = pass * 32 + (t >> 3);
      const int sub = t & 7;
      float f[8];
#pragma unroll
      for (int e = 0; e < 8; ++e) f[e] = kst[key * LP + sub * 8 + e];
      u16 hi[8], lo[8];
#pragma unroll
      for (int e = 0; e < 8; ++e) {
        hi[e] = f2bf(f[e]);
        lo[e] = f2bf(f[e] - bf2f(hi[e]));
      }
      const int c = sub >> 1, g2 = sub & 1;
      u16* row = rowbase + (size_t)key * 128;
      const int sh = ((c * 4 + g2 * 2 + 0) ^ (key & 15)) * 8;
      const int sl = ((c * 4 + g2 * 2 + 1) ^ (key & 15)) * 8;
      uint4 vh = {(u32)hi[0] | ((u32)hi[1] << 16), (u32)hi[2] | ((u32)hi[3] << 16),
                  (u32)hi[4] | ((u32)hi[5] << 16), (u32)hi[6] | ((u32)hi[7] << 16)};
      uint4 vl = {(u32)lo[0] | ((u32)lo[1] << 16), (u32)lo[2] | ((u32)lo[3] << 16),
                  (u32)lo[4] | ((u32)lo[5] << 16), (u32)lo[6] | ((u32)lo[7] << 16)};
      *(uint4*)(row + sh) = vh;
      *(uint4*)(row + sl) = vl;
    }
  }

  {
    const int d = t & 63, rr = t >> 6;
    float s = 0.f;
#pragma unroll
    for (int i = 0; i < 16; ++i) s += kst[(rr * 16 + i) * LP + d];
    red[rr][d] = s;
  }
  __syncthreads();
  {
    const int d = t & 63, rr = t >> 6;
    if (rr == 0) {
      float tot = red[0][d] + red[1][d] + red[2][d] + red[3][d];
      pkp[((size_t)h * NBLK + kb) * D + d] = tot * (1.f / 64.f);
    }
  }

  {
    u16* base = vpkb + (((size_t)h * 64 + kb) * 64) * 128;
#pragma unroll
    for (int iter = 0; iter < 4; ++iter) {
      const int dim = iter * 16 + (t >> 4);
      const int s = t & 15;
      const int cgh = s ^ (dim & 15);
      const int c = cgh >> 2, g = (cgh >> 1) & 1, hl = cgh & 1;
      u16 o[8];
#pragma unroll
      for (int e = 0; e < 8; ++e) {
        const int key = 4 * g + (e & 3) + 8 * ((e >> 2) + 2 * (c & 1)) + 32 * (c >> 1);
        float val = vst[key * LP + dim];
        u16 hi = f2bf(val);
        o[e] = hl ? f2bf(val - bf2f(hi)) : hi;
      }
      uint4 pk4 = {(u32)o[0] | ((u32)o[1] << 16), (u32)o[2] | ((u32)o[3] << 16),
                   (u32)o[4] | ((u32)o[5] << 16), (u32)o[6] | ((u32)o[7] << 16)};
      *(uint4*)(base + (size_t)dim * 128 + s * 8) = pk4;
    }
  }

  if (t < 128) {
    const int row = t >> 1, half = t & 1;
    float4 kr[8];
#pragma unroll
    for (int i = 0; i < 8; ++i) kr[i] = *(float4*)&kst[row * LP + half * 32 + i * 4];
    float mxk = -INFINITY;
#pragma unroll
    for (int i = 0; i < 8; ++i)
      mxk = fmaxf(mxk, fmaxf(fmaxf(kr[i].x, kr[i].y), fmaxf(kr[i].z, kr[i].w)));
    mxk = fmaxf(mxk, __shfl_xor(mxk, 1));
    float smk = 0.f;
#pragma unroll
    for (int i = 0; i < 8; ++i) {
      kr[i].x = __expf(kr[i].x - mxk); kr[i].y = __expf(kr[i].y - mxk);
      kr[i].z = __expf(kr[i].z - mxk); kr[i].w = __expf(kr[i].w - mxk);
      smk += kr[i].x + kr[i].y + kr[i].z + kr[i].w;
    }
    smk += __shfl_xor(smk, 1);
    const float inv = 1.f / smk;
#pragma unroll
    for (int i = 0; i < 8; ++i) {
      float4 o = kr[i];
      o.x *= inv; o.y *= inv; o.z *= inv; o.w *= inv;
      *(float4*)&kst[row * LP + half * 32 + i * 4] = o;
    }
  }
  __syncthreads();

  {
    const int d = t & 63, eg = t >> 6;
    float4 acc0 = make_float4(0.f, 0.f, 0.f, 0.f);
    float4 acc1 = acc0, acc2 = acc0, acc3 = acc0;
    float ksacc = 0.f;
#pragma unroll 4
    for (int lr = 0; lr < 64; ++lr) {
      const float wv = kst[lr * LP + d];
      if (eg == 0) ksacc += wv;
      const float4* vr = (const float4*)&vst[lr * LP + eg * 16];
      float4 v0 = vr[0], v1 = vr[1], v2 = vr[2], v3 = vr[3];
      acc0.x += wv * v0.x; acc0.y += wv * v0.y; acc0.z += wv * v0.z; acc0.w += wv * v0.w;
      acc1.x += wv * v1.x; acc1.y += wv * v1.y; acc1.z += wv * v1.z; acc1.w += wv * v1.w;
      acc2.x += wv * v2.x; acc2.y += wv * v2.y; acc2.z += wv * v2.z; acc2.w += wv * v2.w;
      acc3.x += wv * v3.x; acc3.y += wv * v3.y; acc3.z += wv * v3.z; acc3.w += wv * v3.w;
    }
    float* kvb = part_kv + ((size_t)(h * 64 + kb)) * 4096 + (size_t)d * 64 + eg * 16;
    *(float4*)(kvb + 0) = acc0;
    *(float4*)(kvb + 4) = acc1;
    *(float4*)(kvb + 8) = acc2;
    *(float4*)(kvb + 12) = acc3;
    if (eg == 0) part_ks[(size_t)(h * 64 + kb) * 64 + d] = ksacc;
  }
}

// ---------------------------------------------------------------------------
// TOPKQ: fused pool_q + top-16 (unchanged from r8)
// ---------------------------------------------------------------------------
__global__ __launch_bounds__(256) void topkq_kernel(
    const float* __restrict__ q, const float* __restrict__ pk,
    int* __restrict__ lut) {
  const int qb = blockIdx.x, h = blockIdx.y;
  __shared__ float red[4][64];
  __shared__ alignas(16) float pqv[64];
  const int t = threadIdx.x;
  const int d = t & 63, rr = t >> 6;
  {
    const float* base = q + ((size_t)h * L + (size_t)qb * 64) * D;
    float s = 0.f;
#pragma unroll
    for (int i = 0; i < 16; ++i) s += base[(rr * 16 + i) * D + d];
    red[rr][d] = s;
  }
  __syncthreads();
  if (rr == 0)
    pqv[d] = (red[0][d] + red[1][d] + red[2][d] + red[3][d]) * (1.f / 64.f);
  __syncthreads();
  if (t < 64) {
    const int j = t;
    const float4* pq4 = (const float4*)pqv;
    const float4* pk4 = (const float4*)(pk + ((size_t)h * NBLK + j) * D);
    float sc = 0.f;
#pragma unroll
    for (int d4 = 0; d4 < 16; ++d4) sc += dot4f(pq4[d4], pk4[d4]);
    int* lrow = lut + ((size_t)h * NBLK + qb) * TOPK;
    for (int it = 0; it < TOPK; ++it) {
      float m = sc;
      int mi = j;
#pragma unroll
      for (int off = 32; off; off >>= 1) {
        float om = __shfl_xor(m, off);
        int omi = __shfl_xor(mi, off);
        if (om > m || (om == m && omi < mi)) { m = om; mi = omi; }
      }
      if (j == 0) lrow[it] = mi;
      if (j == mi) sc = -INFINITY;
    }
  }
}

// ---------------------------------------------------------------------------
// SATTN v5b: 512-thread blocks (8 waves), 2 K-blocks per iteration.
// Wave w: panel p=w&1, key-half kh=(w>>1)&1, tile j=w>>2 (== its staging half).
// FIXED from r8: full 16KB tiles (1024 uint4): pf[8], 4 uint4/thread per
// array, lv = lk + 1024. Single 64KB buffer, 2 blocks/CU -> 16 waves/CU.
// ---------------------------------------------------------------------------
__global__ __launch_bounds__(512, 4) void sattn_kernel(
    const float* __restrict__ q, const u16* __restrict__ kpk,
    const u16* __restrict__ vpk, const int* __restrict__ lut,
    float* __restrict__ out) {
  __shared__ alignas(16) char smem[65536];  // [2 tiles][K 16KB | V 16KB]
  const int bx = blockIdx.x;
  const int h = bx & 7, qb = bx >> 3;  // XCD swizzle: head -> one XCD's L2
  const int t = threadIdx.x;
  const int lane = t & 63;
  const int ln = lane & 31;
  const int g = lane >> 5;
  const int w = t >> 6;
  const int p = w & 1;
  const int kh = (w >> 1) & 1;
  const int j = w >> 2;            // == t>>8: this thread's staging tile too
  const int th = t & 255;

  // --- Q hi/lo fragments straight from global (L2-hot) ---
  bf16x8 qh[4], ql[4];
  {
    const float* qrowp = q + ((size_t)h * L + (size_t)qb * 64 + p * 32 + ln) * D;
#pragma unroll
    for (int c = 0; c < 4; ++c) {
      float4 a = *(const float4*)(qrowp + c * 16 + g * 8);
      float4 b = *(const float4*)(qrowp + c * 16 + g * 8 + 4);
      float f[8] = {a.x, a.y, a.z, a.w, b.x, b.y, b.z, b.w};
#pragma unroll
      for (int e = 0; e < 8; ++e) {
        float x = f[e] * 0.125f;
        u16 hi = f2bf(x);
        qh[c][e] = (short)hi;
        ql[c][e] = (short)f2bf(x - bf2f(hi));
      }
    }
  }

  const u16* KB = (const u16*)smem + j * 16384;  // this wave's tile (u16 elems)
  const u16* VB = KB + 8192;                     // +16KB
  uint4* lk = (uint4*)((u16*)smem + j * 16384);  // half stages its own tile
  uint4* lv = lk + 1024;                         // V tile starts after 1024 uint4

  f32x16 o0, o1;
#pragma unroll
  for (int r = 0; r < 16; ++r) { o0[r] = 0.f; o1[r] = 0.f; }
  float lrun = 0.f;
  const int* lrow = lut + ((size_t)h * NBLK + qb) * TOPK;
  const int xr = ln & 15;
  const int krow = kh * 32 + ln;

  uint4 pf[8];
#define LOADR(ibi)                                                               \
  {                                                                              \
    const int kb_ = lrow[2 * (ibi) + j];                                         \
    const uint4* gk = (const uint4*)(kpk + ((size_t)h * L + (size_t)kb_ * 64) * 128); \
    const uint4* gv = (const uint4*)(vpk + (((size_t)h * 64 + kb_) * 64) * 128);      \
    _Pragma("unroll") for (int i_ = 0; i_ < 4; ++i_) {                           \
      pf[i_] = gk[i_ * 256 + th];                                                \
      pf[4 + i_] = gv[i_ * 256 + th];                                            \
    }                                                                            \
  }
#define WRITES                                                                   \
  {                                                                              \
    _Pragma("unroll") for (int i_ = 0; i_ < 4; ++i_) {                           \
      lk[i_ * 256 + th] = pf[i_];                                                \
      lv[i_ * 256 + th] = pf[4 + i_];                                            \
    }                                                                            \
  }

  LOADR(0);
  WRITES;            // compiler inserts vmcnt wait before ds_write
  LOADR(1);          // prefetch pair 1 into regs
  __syncthreads();

  for (int ib = 0; ib < 8; ++ib) {
    // ---- S^T = K . Q^T over this wave's 32-key half of tile j ----
    f32x16 s0;
#pragma unroll
    for (int r = 0; r < 16; ++r) s0[r] = 0.f;
    __builtin_amdgcn_s_setprio(1);
#pragma unroll
    for (int c = 0; c < 4; ++c) {
      const int sH = c * 4 + g * 2;
      bf16x8 k_h = *(const bf16x8*)(KB + (size_t)krow * 128 + ((sH ^ xr) * 8));
      bf16x8 k_l = *(const bf16x8*)(KB + (size_t)krow * 128 + (((sH + 1) ^ xr) * 8));
      s0 = __builtin_amdgcn_mfma_f32_32x32x16_bf16(k_h, qh[c], s0, 0, 0, 0);
      s0 = __builtin_amdgcn_mfma_f32_32x32x16_bf16(k_l, qh[c], s0, 0, 0, 0);
      s0 = __builtin_amdgcn_mfma_f32_32x32x16_bf16(k_h, ql[c], s0, 0, 0, 0);
    }
    __builtin_amdgcn_s_setprio(0);

    // ---- P = exp(S) (no max; scores bounded), pack hi/lo via cvt_pk ----
    u32 hpk[8], lpk[8];
    float psum = 0.f;
#pragma unroll
    for (int jj = 0; jj < 8; ++jj) {
      float a = __expf(s0[2 * jj]);
      float b = __expf(s0[2 * jj + 1]);
      psum += a + b;
      u32 hp;
      asm("v_cvt_pk_bf16_f32 %0, %1, %2" : "=v"(hp) : "v"(a), "v"(b));
      hpk[jj] = hp;
      float ah = __uint_as_float(hp << 16);
      float bh = __uint_as_float(hp & 0xffff0000u);
      u32 lp;
      asm("v_cvt_pk_bf16_f32 %0, %1, %2" : "=v"(lp) : "v"(a - ah), "v"(b - bh));
      lpk[jj] = lp;
    }
    psum += __shfl_xor(psum, 32);
    lrun += psum;

    // ---- PV over this wave's key channels ----
    __builtin_amdgcn_s_setprio(1);
#pragma unroll
    for (int cc = 0; cc < 2; ++cc) {
      union { u32x4 u; bf16x8 b; } ph, pl;
      ph.u = (u32x4){hpk[4 * cc + 0], hpk[4 * cc + 1], hpk[4 * cc + 2], hpk[4 * cc + 3]};
      pl.u = (u32x4){lpk[4 * cc + 0], lpk[4 * cc + 1], lpk[4 * cc + 2], lpk[4 * cc + 3]};
      const bf16x8 pah = ph.b, pal = pl.b;
      const int sH = (2 * kh + cc) * 4 + g * 2;
      bf16x8 v0h = *(const bf16x8*)(VB + (size_t)ln * 128 + ((sH ^ xr) * 8));
      bf16x8 v0l = *(const bf16x8*)(VB + (size_t)ln * 128 + (((sH + 1) ^ xr) * 8));
      bf16x8 v1h = *(const bf16x8*)(VB + (size_t)(32 + ln) * 128 + ((sH ^ xr) * 8));
      bf16x8 v1l = *(const bf16x8*)(VB + (size_t)(32 + ln) * 128 + (((sH + 1) ^ xr) * 8));
      o0 = __builtin_amdgcn_mfma_f32_32x32x16_bf16(pah, v0h, o0, 0, 0, 0);
      o0 = __builtin_amdgcn_mfma_f32_32x32x16_bf16(pal, v0h, o0, 0, 0, 0);
      o0 = __builtin_amdgcn_mfma_f32_32x32x16_bf16(pah, v0l, o0, 0, 0, 0);
      o1 = __builtin_amdgcn_mfma_f32_32x32x16_bf16(pah, v1h, o1, 0, 0, 0);
      o1 = __builtin_amdgcn_mfma_f32_32x32x16_bf16(pal, v1h, o1, 0, 0, 0);
      o1 = __builtin_amdgcn_mfma_f32_32x32x16_bf16(pah, v1l, o1, 0, 0, 0);
    }
    __builtin_amdgcn_s_setprio(0);

    __syncthreads();                     // all reads of current tiles done
    if (ib + 1 < 8) { WRITES; }          // write pair ib+1 (waits its vmcnt)
    if (ib + 2 < 8) LOADR(ib + 2);       // prefetch pair ib+2 into regs
    __syncthreads();                     // writes visible
  }
#undef LOADR
#undef WRITES

  // ---- merge (kh,j) quadrants: plain sums, normalize, store ----
  float* oxb = (float*)smem;             // [2p][3 slots][32][64] = 48KB
  float* lxb = (float*)smem + 12288;     // [2p][4][32]
  __syncthreads();  // smem reuse
  const int cmb = kh + 2 * j;
  if (g == 0) lxb[(p * 4 + cmb) * 32 + ln] = lrun;
  if (cmb != 0) {
#pragma unroll
    for (int r = 0; r < 16; ++r) {
      const int R = (r & 3) + 8 * (r >> 2) + 4 * g;
      oxb[(p * 3 + cmb - 1) * 2048 + R * 64 + ln] = o0[r];
      oxb[(p * 3 + cmb - 1) * 2048 + R * 64 + 32 + ln] = o1[r];
    }
  }
  __syncthreads();
  if (cmb == 0) {
#pragma unroll
    for (int r = 0; r < 16; ++r) {
      const int R = (r & 3) + 8 * (r >> 2) + 4 * g;
      const float lt = lxb[(p * 4 + 0) * 32 + R] + lxb[(p * 4 + 1) * 32 + R] +
                       lxb[(p * 4 + 2) * 32 + R] + lxb[(p * 4 + 3) * 32 + R];
      const float inv = 1.f / lt;
      float a0 = o0[r], a1 = o1[r];
#pragma unroll
      for (int s = 0; s < 3; ++s) {
        a0 += oxb[(p * 3 + s) * 2048 + R * 64 + ln];
        a1 += oxb[(p * 3 + s) * 2048 + R * 64 + 32 + ln];
      }
      const size_t row = (size_t)h * L + (size_t)qb * 64 + p * 32 + R;
      out[row * 64 + ln] = a0 * inv;
      out[row * 64 + 32 + ln] = a1 * inv;
    }
  }
}

// ---------------------------------------------------------------------------
// KVPROJ: reduce all 64 partials/head + fold projection kvp = kv @ W^T. grid 8.
// ---------------------------------------------------------------------------
__global__ __launch_bounds__(256) void kvproj_kernel(
    const float* __restrict__ part_kv, const float* __restrict__ part_ks,
    const float* __restrict__ pw, float* __restrict__ kvp,
    float* __restrict__ ksum) {
  const int h = blockIdx.x;
  __shared__ float kvs[64 * 64];
  __shared__ float pws[64 * 64];
  const int t = threadIdx.x;
  float4 s0 = make_float4(0.f, 0.f, 0.f, 0.f);
  float4 s1 = s0, s2 = s0, s3 = s0;
  for (int p = 0; p < 64; ++p) {
    const float4* src = (const float4*)(part_kv + ((size_t)(h * 64 + p)) * 4096);
    float4 a = src[0 * 256 + t], b = src[1 * 256 + t];
    float4 cc = src[2 * 256 + t], dd = src[3 * 256 + t];
    s0.x += a.x; s0.y += a.y; s0.z += a.z; s0.w += a.w;
    s1.x += b.x; s1.y += b.y; s1.z += b.z; s1.w += b.w;
    s2.x += cc.x; s2.y += cc.y; s2.z += cc.z; s2.w += cc.w;
    s3.x += dd.x; s3.y += dd.y; s3.z += dd.z; s3.w += dd.w;
  }
  ((float4*)kvs)[0 * 256 + t] = s0;
  ((float4*)kvs)[1 * 256 + t] = s1;
  ((float4*)kvs)[2 * 256 + t] = s2;
  ((float4*)kvs)[3 * 256 + t] = s3;
#pragma unroll
  for (int i = 0; i < 4; ++i) {
    int f4 = i * 256 + t;
    ((float4*)pws)[f4] = ((const float4*)pw)[f4];
  }
  if (t < 64) {
    float ks = 0.f;
    for (int p = 0; p < 64; ++p) ks += part_ks[(size_t)(h * 64 + p) * 64 + t];
    ksum[(size_t)h * 64 + t] = ks;
  }
  __syncthreads();
  const int d = t & 63, fg = t >> 6;
  float* dst = kvp + (size_t)h * 4096 + (size_t)d * 64;
  const float4* a = (const float4*)&kvs[d * 64];
  for (int f = fg * 16; f < fg * 16 + 16; ++f) {
    const float4* b = (const float4*)&pws[f * 64];
    float s = 0.f;
#pragma unroll
    for (int e4 = 0; e4 < 16; ++e4) s += dot4f(a[e4], b[e4]);
    dst[f] = s;
  }
}

// ---------------------------------------------------------------------------
// LINATTN: out += o_l + bias (RMW; sattn wrote o_s)
// ---------------------------------------------------------------------------
__global__ __launch_bounds__(256) void linattn_kernel(
    const float* __restrict__ q, const float* __restrict__ kvp,
    const float* __restrict__ ksum, const float* __restrict__ pb,
    float* __restrict__ out) {
  __shared__ float kvs[64 * 64];
  __shared__ float kss[64], pbs[64];
  const int t = threadIdx.x;
  const size_t grow = (size_t)blockIdx.x * 256 + t;
  const int h = (int)(grow >> 12);
#pragma unroll
  for (int i = 0; i < 4; ++i) {
    int f4 = i * 256 + t;
    ((float4*)kvs)[f4] = ((const float4*)(kvp + (size_t)h * 4096))[f4];
  }
  if (t < 64) {
    kss[t] = ksum[(size_t)h * 64 + t];
    pbs[t] = pb[t];
  }
  __syncthreads();
  const float* qrow = q + grow * 64;
  float mx = -INFINITY;
  const float4* q4p = (const float4*)qrow;
#pragma unroll
  for (int i = 0; i < 16; ++i) {
    float4 x = q4p[i];
    mx = fmaxf(mx, fmaxf(fmaxf(x.x, x.y), fmaxf(x.z, x.w)));
  }
  float4 tt[16];
#pragma unroll
  for (int i = 0; i < 16; ++i) tt[i] = make_float4(0.f, 0.f, 0.f, 0.f);
  float sm = 0.f, dn = 0.f;
#pragma unroll 4
  for (int dd = 0; dd < 64; ++dd) {
    const float wv = __expf(qrow[dd] - mx);
    sm += wv;
    dn += wv * kss[dd];
    const float4* kvr = (const float4*)&kvs[dd * 64];
#pragma unroll
    for (int e4 = 0; e4 < 16; ++e4) {
      float4 kk = kvr[e4];
      tt[e4].x += wv * kk.x; tt[e4].y += wv * kk.y;
      tt[e4].z += wv * kk.z; tt[e4].w += wv * kk.w;
    }
  }
  const float inv = 1.f / (dn + EPS * sm);
  float* orow = out + grow * 64;
#pragma unroll
  for (int e4 = 0; e4 < 16; ++e4) {
    float4 o = ((float4*)orow)[e4];
    o.x += tt[e4].x * inv + pbs[e4 * 4 + 0];
    o.y += tt[e4].y * inv + pbs[e4 * 4 + 1];
    o.z += tt[e4].z * inv + pbs[e4 * 4 + 2];
    o.w += tt[e4].w * inv + pbs[e4 * 4 + 3];
    ((float4*)orow)[e4] = o;
  }
}

// ---------------------------------------------------------------------------
extern "C" void kernel_launch(void* const* d_in, const int* in_sizes, int n_in,
                              void* d_out, int out_size, void* d_ws, size_t ws_size,
                              hipStream_t stream) {
  const float* q = (const float*)d_in[0];
  const float* k = (const float*)d_in[1];
  const float* v = (const float*)d_in[2];
  const float* pw = (const float*)d_in[3];
  const float* pb = (const float*)d_in[4];
  float* out = (float*)d_out;

  u16* kpkb = (u16*)d_ws;
  u16* vpkb = (u16*)d_ws + 4194304;
  float* fws = (float*)((char*)d_ws + 16777216);
  float* pk = fws + 32768;               // pooled K
  float* part_kv = fws + 65536;          // 2097152
  float* part_ks = fws + 2162688;        // 32768
  float* kvp = fws + 2727936;            // 32768
  float* ksum = fws + 2760704;           // 512
  int* lut = (int*)(fws + 2761216);      // 8192 ints

  kvprep_kernel<<<dim3(64, 8), 256, 0, stream>>>(k, v, kpkb, vpkb, pk, part_kv, part_ks);
  topkq_kernel<<<dim3(64, 8), 256, 0, stream>>>(q, pk, lut);
  sattn_kernel<<<512, 512, 0, stream>>>(q, kpkb, vpkb, lut, out);
  kvproj_kernel<<<8, 256, 0, stream>>>(part_kv, part_ks, pw, kvp, ksum);
  linattn_kernel<<<128, 256, 0, stream>>>(q, kvp, ksum, pb, out);
}